// Round 4
// baseline (253.873 us; speedup 1.0000x reference)
//
#include <hip/hip_runtime.h>
#include <hip/hip_bf16.h>

#define IN_F 512
#define OUT_F 512
#define LATD 512
#define RES 64
#define BATCH 8
#define EPSV 1e-8f

static constexpr float C_LIN  = 0.04419417382415922f;   // 1/sqrt(512)
static constexpr float C_CONV = 0.014731391274719739f;  // 1/sqrt(512*9)

#define PLANE 139392   // 66 rows * 132 units * 16 B   (one (c16,b) halo plane)

typedef __attribute__((ext_vector_type(8)))  short short8;
typedef __attribute__((ext_vector_type(16))) float f32x16;

union BF { __hip_bfloat16 h; short s; };

__device__ __forceinline__ void async_load16(const char* g, char* l) {
  __builtin_amdgcn_global_load_lds(
      (const __attribute__((address_space(1))) unsigned int*)g,
      (__attribute__((address_space(3))) unsigned int*)l, 16, 0, 0);
}

// ---------------- s = latent @ (w_lin*C).T + b_lin ----------------
__global__ void k_compute_s(const float* __restrict__ latent,
                            const float* __restrict__ w_lin,
                            const float* __restrict__ b_lin,
                            float* __restrict__ s) {
  const int i = blockIdx.x * 4 + (threadIdx.x >> 6);
  const int lane = threadIdx.x & 63;
  const float4* wl = (const float4*)(w_lin + (size_t)i * LATD);
  const float4 w0 = wl[lane * 2], w1 = wl[lane * 2 + 1];
  float acc[BATCH];
#pragma unroll
  for (int b = 0; b < BATCH; ++b) {
    const float4* lt = (const float4*)(latent + (size_t)b * LATD);
    const float4 l0 = lt[lane * 2], l1 = lt[lane * 2 + 1];
    acc[b] = w0.x * l0.x + w0.y * l0.y + w0.z * l0.z + w0.w * l0.w +
             w1.x * l1.x + w1.y * l1.y + w1.z * l1.z + w1.w * l1.w;
  }
#pragma unroll
  for (int b = 0; b < BATCH; ++b) {
    float v = acc[b];
#pragma unroll
    for (int off = 32; off > 0; off >>= 1) v += __shfl_down(v, off);
    if (lane == 0) s[b * IN_F + i] = v * C_LIN + b_lin[i];
  }
}

// ---- wb[c][ob][tap][u][ol][8ch] = bf16(w_conv*C) ; w2[o][i] = sum_t w^2 ----
__global__ void k_prep_w(const float* __restrict__ w_conv,
                         short* __restrict__ wb,
                         float* __restrict__ w2) {
  const int t = blockIdx.x * 256 + threadIdx.x;   // 262144: o*512 + i
  const int o = t >> 9;
  const int i = t & 511;
  const float* src = w_conv + (size_t)t * 9;
  const int c = i >> 4, u = (i >> 3) & 1, i8 = i & 7;
  const int ob = o >> 6, ol = o & 63;
  float sum = 0.f;
#pragma unroll
  for (int tap = 0; tap < 9; ++tap) {
    const float v = src[tap] * C_CONV;
    sum += v * v;
    BF cv; cv.h = __float2bfloat16(v);
    wb[((((size_t)(c * 8 + ob) * 9 + tap) * 2 + u) * 64 + ol) * 8 + i8] = cv.s;
  }
  w2[t] = sum;
}

// ---- sigma_inv[b][o] = rsqrt(sum_i w2[o][i]*s[b][i]^2 + eps) ----
__global__ void k_sigma(const float* __restrict__ w2,
                        const float* __restrict__ s,
                        float* __restrict__ sigma_inv) {
  const int o = blockIdx.x * 4 + (threadIdx.x >> 6);
  const int lane = threadIdx.x & 63;
  float acc[BATCH];
#pragma unroll
  for (int b = 0; b < BATCH; ++b) acc[b] = 0.f;
#pragma unroll
  for (int k = 0; k < 8; ++k) {
    const int i = k * 64 + lane;
    const float w = w2[o * IN_F + i];
#pragma unroll
    for (int b = 0; b < BATCH; ++b) {
      const float sv = s[b * IN_F + i];
      acc[b] += w * sv * sv;
    }
  }
#pragma unroll
  for (int b = 0; b < BATCH; ++b) {
    float v = acc[b];
#pragma unroll
    for (int off = 32; off > 0; off >>= 1) v += __shfl_down(v, off);
    if (lane == 0) sigma_inv[b * OUT_F + o] = rsqrtf(v + EPSV);
  }
}

// ---- xmp[c][b][h+1][u][w+1][16B] = bf16(x * s), borders zeroed ----
__global__ void k_modulate(const float* __restrict__ x,
                           const float* __restrict__ s,
                           char* __restrict__ xmp) {
  const int h    = blockIdx.x & 63;
  const int ic32 = (blockIdx.x >> 6) & 15;
  const int b    = blockIdx.x >> 10;
  __shared__ float tile[32][65];
  const int tid = threadIdx.x;
  {
    const int il = tid >> 3, w8 = (tid & 7) * 8;
    const int i = ic32 * 32 + il;
    const float sv = s[b * IN_F + i];
    const float* xp = x + (((size_t)(b * IN_F + i) * RES + h) * RES + w8);
    const float4 v0 = *(const float4*)xp;
    const float4 v1 = *(const float4*)(xp + 4);
    tile[il][w8 + 0] = v0.x * sv; tile[il][w8 + 1] = v0.y * sv;
    tile[il][w8 + 2] = v0.z * sv; tile[il][w8 + 3] = v0.w * sv;
    tile[il][w8 + 4] = v1.x * sv; tile[il][w8 + 5] = v1.y * sv;
    tile[il][w8 + 6] = v1.z * sv; tile[il][w8 + 7] = v1.w * sv;
  }
  __syncthreads();
  {
    const int chalf = tid >> 7, u = (tid >> 6) & 1, w = tid & 63;
    short8 pk;
#pragma unroll
    for (int j = 0; j < 8; ++j) {
      BF cv; cv.h = __float2bfloat16(tile[chalf * 16 + u * 8 + j][w]);
      pk[j] = cv.s;
    }
    const int c = ic32 * 2 + chalf;
    char* dst = xmp + (size_t)(c * 8 + b) * PLANE +
                ((size_t)(h + 1) * 132 + u * 66 + (w + 1)) * 16;
    *(short8*)dst = pk;
  }
  // fused border zeroing (no sync needed; disjoint cells)
  const uint4 z = make_uint4(0u, 0u, 0u, 0u);
  if (tid < 8) {  // left/right columns of this row
    const int chalf = tid & 1, u = (tid >> 1) & 1, wsel = tid >> 2;
    char* dst = xmp + (size_t)((ic32 * 2 + chalf) * 8 + b) * PLANE +
                ((size_t)(h + 1) * 132 + u * 66 + (wsel ? 65 : 0)) * 16;
    *(uint4*)dst = z;
  }
  if (h == 0 || h == 63) {
    const int row = (h == 0) ? 0 : 65;
    for (int idx = tid; idx < 264; idx += 256) {   // 2 chalf x 132 units
      const int chalf = idx / 132, uu = idx - chalf * 132;
      char* dst = xmp + (size_t)((ic32 * 2 + chalf) * 8 + b) * PLANE +
                  ((size_t)row * 132 + uu) * 16;
      *(uint4*)dst = z;
    }
  }
}

// ---------------- main implicit-GEMM conv ----------------
// Block: 64 o x (8 rows x 64 cols), 4 waves (wave = 2 rows = 128 px).
// MFMA 32x32x16: A = weights (m=o), B = pixels (n=px). K=16 chunks,
// double-buffered LDS, 1 barrier/chunk. Lane-order-contiguous LDS layout
// ([u][idx][16B]) -> conflict-free ds_read_b128; staging is identity copy.
__global__ __launch_bounds__(256, 2)
void k_conv(const char* __restrict__ xmp,
            const short* __restrict__ wbg,
            const float* __restrict__ sigma_inv,
            const float* __restrict__ b_conv,
            float* __restrict__ out) {
  __shared__ __align__(16) char lds[79104];  // x: 2*21120, w: 2*18432 @42240
  // XCD swizzle: the 8 o-blocks sharing one x tile get bids = g (mod 8 equal)
  const int bid = blockIdx.x;
  const int g = bid & 63;        // (b, h0) group
  const int ob = bid >> 6;       // o-block 0..7
  const int o0 = ob * 64;
  const int b  = g >> 3;
  const int h0 = (g & 7) * 8;
  const int tid = threadIdx.x;
  const int wave = tid >> 6, lane = tid & 63;
  const int l31 = lane & 31, half = lane >> 5;

  f32x16 acc[2][4];
#pragma unroll
  for (int i = 0; i < 2; ++i)
#pragma unroll
    for (int j = 0; j < 4; ++j)
#pragma unroll
      for (int r = 0; r < 16; ++r) acc[i][j][r] = 0.f;

  const char* xsrc0 = xmp + (size_t)b * PLANE + (size_t)h0 * 2112;   // + ic*8*PLANE
  const char* wsrc0 = (const char*)wbg + (size_t)ob * 18432;          // + ic*8*18432

  // stage chunk 0 into parity 0
#pragma unroll
  for (int k = 0; k < 5; ++k) {
    const int j = tid + k * 256;
    async_load16(xsrc0 + j * 16, lds + j * 16);
  }
  if (tid < 40) { const int j = 1280 + tid; async_load16(xsrc0 + j * 16, lds + j * 16); }
#pragma unroll
  for (int k = 0; k < 4; ++k) {
    const int j = tid + k * 256;
    async_load16(wsrc0 + j * 16, lds + 42240 + j * 16);
  }
  if (tid < 128) { const int j = 1024 + tid; async_load16(wsrc0 + j * 16, lds + 42240 + j * 16); }
  __syncthreads();

  for (int ic = 0; ic < 32; ++ic) {
    const int p = ic & 1;
    if (ic + 1 < 32) {     // prefetch next chunk into parity p^1
      const char* xs  = xsrc0 + (size_t)(ic + 1) * (8 * PLANE);
      const char* wsr = wsrc0 + (size_t)(ic + 1) * (8 * 18432);
      char* xd = lds + (p ^ 1) * 21120;
      char* wd = lds + 42240 + (p ^ 1) * 18432;
#pragma unroll
      for (int k = 0; k < 5; ++k) {
        const int j = tid + k * 256;
        async_load16(xs + j * 16, xd + j * 16);
      }
      if (tid < 40) { const int j = 1280 + tid; async_load16(xs + j * 16, xd + j * 16); }
#pragma unroll
      for (int k = 0; k < 4; ++k) {
        const int j = tid + k * 256;
        async_load16(wsr + j * 16, wd + j * 16);
      }
      if (tid < 128) { const int j = 1024 + tid; async_load16(wsr + j * 16, wd + j * 16); }
    }
    const char* xp = lds + p * 21120;
    const char* wp = lds + 42240 + p * 18432;
#pragma unroll
    for (int tap = 0; tap < 9; ++tap) {
      const int dh = tap / 3, dw = tap - dh * 3;
      // A: [tap][u=half][ol][16B] — unit index == lane order, conflict-free
      const short8 a0 = *(const short8*)(wp + (tap * 128 + half * 64 + l31) * 16);
      const short8 a1 = *(const short8*)(wp + (tap * 128 + half * 64 + 32 + l31) * 16);
#pragma unroll
      for (int tp = 0; tp < 4; ++tp) {
        const int hr = wave * 2 + (tp >> 1) + dh;
        const int px = (tp & 1) * 32 + dw + l31;
        // B: [hr][u=half][px][16B]
        const short8 bf = *(const short8*)(xp + ((size_t)hr * 132 + half * 66 + px) * 16);
        acc[0][tp] = __builtin_amdgcn_mfma_f32_32x32x16_bf16(a0, bf, acc[0][tp], 0, 0, 0);
        acc[1][tp] = __builtin_amdgcn_mfma_f32_32x32x16_bf16(a1, bf, acc[1][tp], 0, 0, 0);
      }
    }
    __syncthreads();
  }

  // epilogue: C/D col(lane&31) = px, row = o_local = (reg&3) + 8*(reg>>2) + 4*half + 32*t_o
#pragma unroll
  for (int t_o = 0; t_o < 2; ++t_o) {
#pragma unroll
    for (int gg = 0; gg < 4; ++gg) {
#pragma unroll
      for (int r = 0; r < 4; ++r) {
        const int o = o0 + t_o * 32 + r + 8 * gg + 4 * half;
        const float sig  = sigma_inv[b * OUT_F + o];
        const float bias = b_conv[o];
        const int reg = gg * 4 + r;
#pragma unroll
        for (int tp = 0; tp < 4; ++tp) {
          const int h = h0 + wave * 2 + (tp >> 1);
          const int w = (tp & 1) * 32 + l31;
          out[(((size_t)(b * OUT_F + o) * RES + h) * RES) + w] =
              acc[t_o][tp][reg] * sig + bias;
        }
      }
    }
  }
}

extern "C" void kernel_launch(void* const* d_in, const int* in_sizes, int n_in,
                              void* d_out, int out_size, void* d_ws, size_t ws_size,
                              hipStream_t stream) {
  const float* x      = (const float*)d_in[0];
  const float* latent = (const float*)d_in[1];
  const float* w_lin  = (const float*)d_in[2];
  const float* b_lin  = (const float*)d_in[3];
  const float* w_conv = (const float*)d_in[4];
  const float* b_conv = (const float*)d_in[5];
  float* out = (float*)d_out;

  char* ws = (char*)d_ws;
  char*  xmp       = ws;                            // 35,684,352 B (256 planes x 139392)
  short* wb        = (short*)(ws + 35684352);       //  4,718,592 B
  float* w2        = (float*)(ws + 40402944);       //  1,048,576 B
  float* s         = (float*)(ws + 41451520);       //     16,384 B
  float* sigma_inv = (float*)(ws + 41467904);       //     16,384 B

  k_compute_s<<<IN_F / 4, 256, 0, stream>>>(latent, w_lin, b_lin, s);
  k_prep_w<<<1024, 256, 0, stream>>>(w_conv, wb, w2);
  k_sigma<<<128, 256, 0, stream>>>(w2, s, sigma_inv);
  k_modulate<<<BATCH * 16 * RES, 256, 0, stream>>>(x, s, xmp);
  k_conv<<<512, 256, 0, stream>>>(xmp, wb, sigma_inv, b_conv, out);
}